// Round 12
// baseline (784.826 us; speedup 1.0000x reference)
//
#include <hip/hip_runtime.h>

typedef __bf16  bf16x8 __attribute__((ext_vector_type(8)));
typedef float   f32x4  __attribute__((ext_vector_type(4)));
typedef unsigned int uint32x2 __attribute__((ext_vector_type(2)));

#define MFMA16(a,b,c) __builtin_amdgcn_mfma_f32_16x16x32_bf16((a),(b),(c),0,0,0)

// bf16 weight arena layout in d_ws (elements), Wt[n][k] with k padded
enum : int {
    OFF_W0 = 0,                      // [256][64]
    OFF_W1 = OFF_W0 + 256 * 64,      // [256][256]
    OFF_W2 = OFF_W1 + 256 * 256,
    OFF_W3 = OFF_W2 + 256 * 256,
    OFF_W4 = OFF_W3 + 256 * 256,     // [256][320]
    OFF_W5 = OFF_W4 + 256 * 320,
    OFF_W6 = OFF_W5 + 256 * 256,
    OFF_W7 = OFF_W6 + 256 * 256,
    OFF_WF = OFF_W7 + 256 * 256,     // [256][256]
    OFF_WD = OFF_WF + 256 * 256,     // [128][288]
    W_TOTAL = OFF_WD + 128 * 288     // even; table goes at byte 2*W_TOTAL
};

// Trunk layer descriptors (L0..L7 + WF). xKt = #leading kt-steps sourced from
// global x (also the H-index shift); relu for L<8.
__constant__ int cWOff[9] = {OFF_W0, OFF_W1, OFF_W2, OFF_W3, OFF_W4, OFF_W5, OFF_W6, OFF_W7, OFF_WF};
__constant__ int cKp[9]   = {64, 256, 256, 256, 320, 256, 256, 256, 256};
__constant__ int cKT[9]   = {2, 8, 8, 8, 10, 8, 8, 8, 8};
__constant__ int cXKt[9]  = {2, 0, 0, 0, 2, 0, 0, 0, 0};

__device__ __forceinline__ unsigned short f2bf(float f) {
    unsigned int u = __float_as_uint(f);
    u += 0x7FFFu + ((u >> 16) & 1u);
    return (unsigned short)(u >> 16);
}

// Soft barrier: LDS ops visible + rendezvous; global loads stay in flight.
__device__ __forceinline__ void soft_barrier() {
    asm volatile("s_waitcnt lgkmcnt(0)" ::: "memory");
    __builtin_amdgcn_s_barrier();
}

__device__ __forceinline__ void prep_one(const float* __restrict__ src,
                                         unsigned short* __restrict__ dst,
                                         int fout, int Kp, int n1, int n2, int n3,
                                         int idx) {
    int n = idx / Kp;
    int k = idx - n * Kp;
    float v = 0.f;
    if (k < n1)                 v = src[k * fout + n];
    else if (k >= n2 && k < n3) v = src[(k - (n2 - n1)) * fout + n];
    dst[n * Kp + k] = f2bf(v);
}

__global__ void prep_kernel(const float* w0, const float* w1, const float* w2,
                            const float* w3, const float* w4, const float* w5,
                            const float* w6, const float* w7, const float* wf,
                            const float* wd,
                            const float* b0, const float* b1, const float* b2,
                            const float* b3, const float* b4, const float* b5,
                            const float* b6, const float* b7, const float* bfv,
                            unsigned short* dst, const float** tbl) {
    if (blockIdx.x == 0 && threadIdx.x == 0) {
        tbl[0] = b0; tbl[1] = b1; tbl[2] = b2; tbl[3] = b3; tbl[4] = b4;
        tbl[5] = b5; tbl[6] = b6; tbl[7] = b7; tbl[8] = bfv;
    }
    int i = blockIdx.x * 256 + threadIdx.x;
    if (i < 256 * 64)  { prep_one(w0, dst + OFF_W0, 256,  64,  63,  64,  64, i); return; }
    i -= 256 * 64;
    if (i < 256 * 256) { prep_one(w1, dst + OFF_W1, 256, 256, 256, 256, 256, i); return; }
    i -= 256 * 256;
    if (i < 256 * 256) { prep_one(w2, dst + OFF_W2, 256, 256, 256, 256, 256, i); return; }
    i -= 256 * 256;
    if (i < 256 * 256) { prep_one(w3, dst + OFF_W3, 256, 256, 256, 256, 256, i); return; }
    i -= 256 * 256;
    if (i < 256 * 320) { prep_one(w4, dst + OFF_W4, 256, 320,  63,  64, 320, i); return; }
    i -= 256 * 320;
    if (i < 256 * 256) { prep_one(w5, dst + OFF_W5, 256, 256, 256, 256, 256, i); return; }
    i -= 256 * 256;
    if (i < 256 * 256) { prep_one(w6, dst + OFF_W6, 256, 256, 256, 256, 256, i); return; }
    i -= 256 * 256;
    if (i < 256 * 256) { prep_one(w7, dst + OFF_W7, 256, 256, 256, 256, 256, i); return; }
    i -= 256 * 256;
    if (i < 256 * 256) { prep_one(wf, dst + OFF_WF, 256, 256, 256, 256, 256, i); return; }
    i -= 256 * 256;
    if (i < 128 * 288) { prep_one(wd, dst + OFF_WD, 128, 288, 286, 288, 288, i); return; }
}

struct Params {
    const float* x;
    const unsigned short* Wt;
    const float* const* bias9;   // table in d_ws (written by prep_kernel)
    const float* bdv;
    const float* wsv;
    const float* bsv;
    const float* wrv;
    const float* brv;
    float* out;
};

// 64 rows/block, 4 waves, N-split (wave owns 64 cols, NT=4). Swapped MFMA
// (D=[neuron][batch]); dbuf Hs (one 64KB array, halves by offset — an
// array of LDS pointers fails gfx950 codegen); 1 soft barrier/layer.
// KEY CHANGE vs R4-R10: the 9 trunk layers run through ONE runtime-indexed
// loop (desc in __constant__), and the K-loop is a rolled kt+=2 loop with
// manually ping-ponged register sets (no rotation movs, no full unroll).
// Total code ~4 KB -> I$-resident (previous versions fully unrolled ~77
// K-rounds = ~45 KB of straight-line code, thrashing the 32 KB I$).
__global__ __launch_bounds__(256, 2) void nerf_kernel(Params P) {
    __shared__ char Hs[65536];   // two [64][256] bf16 halves, swz ^((row&7)<<4)

    const int t    = threadIdx.x;
    const int lane = t & 63;
    const int wave = t >> 6;      // 0..3
    const int lr   = lane & 15;
    const int lk   = lane >> 4;
    const int lkb  = lk << 4;     // A-read byte offset within 64B col-block
    const int blockRow = blockIdx.x << 6;

    // per-mt row constants (batch row = mt*16 + lr)
    int rowOff[4], swz[4];
    const float* xr[4];
#pragma unroll
    for (int mt = 0; mt < 4; ++mt) {
        int row = (mt << 4) + lr;
        rowOff[mt] = row * 512;
        swz[mt]    = (row & 7) << 4;
        xr[mt]     = P.x + (size_t)(blockRow + row) * 93;
    }

    // x fragment: trunk cols kt*32 + lk*8 + j, zero-padded past col 62
    auto ldXfrag = [&](const float* xrm, int kt) -> bf16x8 {
        int c0 = (kt << 5) + (lk << 3);
        bf16x8 r;
#pragma unroll
        for (int j = 0; j < 8; ++j) {
            int c = c0 + j;
            r[j] = (c < 63) ? (__bf16)xrm[c] : (__bf16)0.f;
        }
        return r;
    };
    auto ldHfrag = [&](const char* buf, int mt, int kt) -> bf16x8 {
        int col = (kt << 6) + lkb;
        return *(const bf16x8*)(buf + rowOff[mt] + (col ^ swz[mt]));
    };

    // ---------------- trunk: L0..L7 + WF, one loop ----------------
#pragma unroll 1
    for (int L = 0; L < 9; ++L) {
        const int Kp  = cKp[L];
        const int KT  = cKT[L];
        const int xKt = cXKt[L];
        const unsigned short* W = P.Wt + cWOff[L];
        const float* bias = P.bias9[L];
        const char* rb = Hs + (((L & 1) ^ 1) << 15);
        char* wb = Hs + ((L & 1) << 15);
        const int cb = wave << 6;

        // per-lane B voffsets (elements): neuron n = cb + nt*16 + lr
        int voff[4];
#pragma unroll
        for (int nt = 0; nt < 4; ++nt)
            voff[nt] = (cb + (nt << 4) + lr) * Kp + (lk << 3);

        // acc init = bias (neuron = cb + nt*16 + lk*4 + e)
        f32x4 acc[4][4];
#pragma unroll
        for (int nt = 0; nt < 4; ++nt) {
            f32x4 bv = *(const f32x4*)(bias + cb + (nt << 4) + (lk << 2));
#pragma unroll
            for (int mt = 0; mt < 4; ++mt) acc[mt][nt] = bv;
        }

        // prologue: kt0 -> E set, kt1 -> O set
        bf16x8 aE[4], aO[4], bE[4], bO[4];
        if (0 < xKt) {
#pragma unroll
            for (int mt = 0; mt < 4; ++mt) aE[mt] = ldXfrag(xr[mt], 0);
        } else {
#pragma unroll
            for (int mt = 0; mt < 4; ++mt) aE[mt] = ldHfrag(rb, mt, 0);
        }
        if (1 < xKt) {
#pragma unroll
            for (int mt = 0; mt < 4; ++mt) aO[mt] = ldXfrag(xr[mt], 1);
        } else {
#pragma unroll
            for (int mt = 0; mt < 4; ++mt) aO[mt] = ldHfrag(rb, mt, 1 - xKt);
        }
#pragma unroll
        for (int nt = 0; nt < 4; ++nt) {
            bE[nt] = *(const bf16x8*)(W + voff[nt]);
            bO[nt] = *(const bf16x8*)(W + voff[nt] + 32);
        }

#pragma unroll 1
        for (int kt = 0; kt < KT; kt += 2) {
            __builtin_amdgcn_s_setprio(1);
#pragma unroll
            for (int nt = 0; nt < 4; ++nt)
#pragma unroll
                for (int mt = 0; mt < 4; ++mt)
                    acc[mt][nt] = MFMA16(bE[nt], aE[mt], acc[mt][nt]);
            __builtin_amdgcn_s_setprio(0);
            {   // refill E with kt+2 (clamped)
                int kE = (kt + 2 < KT) ? kt + 2 : KT - 1;
                if (kE < xKt) {
#pragma unroll
                    for (int mt = 0; mt < 4; ++mt) aE[mt] = ldXfrag(xr[mt], kE);
                } else {
#pragma unroll
                    for (int mt = 0; mt < 4; ++mt) aE[mt] = ldHfrag(rb, mt, kE - xKt);
                }
#pragma unroll
                for (int nt = 0; nt < 4; ++nt)
                    bE[nt] = *(const bf16x8*)(W + voff[nt] + (kE << 5));
            }
            __builtin_amdgcn_s_setprio(1);
#pragma unroll
            for (int nt = 0; nt < 4; ++nt)
#pragma unroll
                for (int mt = 0; mt < 4; ++mt)
                    acc[mt][nt] = MFMA16(bO[nt], aO[mt], acc[mt][nt]);
            __builtin_amdgcn_s_setprio(0);
            {   // refill O with kt+3 (clamped)
                int kO = (kt + 3 < KT) ? kt + 3 : KT - 1;
                if (kO < xKt) {
#pragma unroll
                    for (int mt = 0; mt < 4; ++mt) aO[mt] = ldXfrag(xr[mt], kO);
                } else {
#pragma unroll
                    for (int mt = 0; mt < 4; ++mt) aO[mt] = ldHfrag(rb, mt, kO - xKt);
                }
#pragma unroll
                for (int nt = 0; nt < 4; ++nt)
                    bO[nt] = *(const bf16x8*)(W + voff[nt] + (kO << 5));
            }
        }

        // epilogue: (relu), cvt_pk, one b64 LDS write per tile
        const bool dorelu = (L < 8);
#pragma unroll
        for (int nt = 0; nt < 4; ++nt) {
#pragma unroll
            for (int mt = 0; mt < 4; ++mt) {
                f32x4 v = acc[mt][nt];
                if (dorelu) {
#pragma unroll
                    for (int e = 0; e < 4; ++e) v[e] = fmaxf(v[e], 0.f);
                }
                unsigned int lo, hi;
                asm("v_cvt_pk_bf16_f32 %0, %1, %2" : "=v"(lo) : "v"(v[0]), "v"(v[1]));
                asm("v_cvt_pk_bf16_f32 %0, %1, %2" : "=v"(hi) : "v"(v[2]), "v"(v[3]));
                int colb = (cb + (nt << 4) + (lk << 2)) << 1;
                int off = rowOff[mt] + (colb ^ swz[mt]);
                uint32x2 w2 = {lo, hi};
                *(uint32x2*)(wb + off) = w2;
            }
        }
        soft_barrier();
    }
    // Hs lower half (index 0) = xyz_final (WF out, L=8 wrote half 0),
    // Hs upper half (index 1) = h (L7 out, intact)
    char* HsXF = Hs;             // xyz_final
    char* HsH  = Hs + 32768;     // h

    // sigma = h @ ws + bs  (reads HsH)
    float sig;
    {
        int rr = t >> 2, q = t & 3;
        float sp = 0.f;
#pragma unroll
        for (int j = 0; j < 8; ++j) {
            int cb2 = (q << 6) + (j << 3);
            bf16x8 h8 = *(const bf16x8*)(HsH + ((rr * 512 + (cb2 << 1)) ^ ((rr & 7) << 4)));
#pragma unroll
            for (int e = 0; e < 8; ++e) sp += (float)h8[e] * P.wsv[cb2 + e];
        }
        sp += __shfl_xor(sp, 1);
        sp += __shfl_xor(sp, 2);
        sig = sp + P.bsv[0];
    }
    soft_barrier();   // all sigma reads of HsH done before WD overwrites it

    // ---------------- WD: d = relu([xyz_final | dir] @ wd + bd) ----------------
    // K=288 (kt 0..8; kt8 = dir from x), NT=2 -> HsH cols 0..127
    {
        const unsigned short* W = P.Wt + OFF_WD;
        const int cb = wave << 5;
        int voff[2];
#pragma unroll
        for (int nt = 0; nt < 2; ++nt)
            voff[nt] = (cb + (nt << 4) + lr) * 288 + (lk << 3);

        f32x4 acc[4][2];
#pragma unroll
        for (int nt = 0; nt < 2; ++nt) {
            f32x4 bv = *(const f32x4*)(P.bdv + cb + (nt << 4) + (lk << 2));
#pragma unroll
            for (int mt = 0; mt < 4; ++mt) acc[mt][nt] = bv;
        }

        auto ldDir = [&](const float* xrm) -> bf16x8 {
            int c0 = 63 + (lk << 3);
            bf16x8 r;
#pragma unroll
            for (int j = 0; j < 8; ++j) {
                int c = c0 + j;
                r[j] = (c < 93) ? (__bf16)xrm[c] : (__bf16)0.f;
            }
            return r;
        };

        bf16x8 aE[4], aO[4], bE[2], bO[2];
#pragma unroll
        for (int mt = 0; mt < 4; ++mt) { aE[mt] = ldHfrag(HsXF, mt, 0); aO[mt] = ldHfrag(HsXF, mt, 1); }
#pragma unroll
        for (int nt = 0; nt < 2; ++nt) {
            bE[nt] = *(const bf16x8*)(W + voff[nt]);
            bO[nt] = *(const bf16x8*)(W + voff[nt] + 32);
        }

#pragma unroll 1
        for (int kt = 0; kt < 8; kt += 2) {
            __builtin_amdgcn_s_setprio(1);
#pragma unroll
            for (int nt = 0; nt < 2; ++nt)
#pragma unroll
                for (int mt = 0; mt < 4; ++mt)
                    acc[mt][nt] = MFMA16(bE[nt], aE[mt], acc[mt][nt]);
            __builtin_amdgcn_s_setprio(0);
            {
                int kE = kt + 2;   // <= 8
                if (kE == 8) {
#pragma unroll
                    for (int mt = 0; mt < 4; ++mt) aE[mt] = ldDir(xr[mt]);
                } else {
#pragma unroll
                    for (int mt = 0; mt < 4; ++mt) aE[mt] = ldHfrag(HsXF, mt, kE);
                }
#pragma unroll
                for (int nt = 0; nt < 2; ++nt)
                    bE[nt] = *(const bf16x8*)(W + voff[nt] + (kE << 5));
            }
            __builtin_amdgcn_s_setprio(1);
#pragma unroll
            for (int nt = 0; nt < 2; ++nt)
#pragma unroll
                for (int mt = 0; mt < 4; ++mt)
                    acc[mt][nt] = MFMA16(bO[nt], aO[mt], acc[mt][nt]);
            __builtin_amdgcn_s_setprio(0);
            {
                int kO = (kt + 3 < 8) ? kt + 3 : 7;
#pragma unroll
                for (int mt = 0; mt < 4; ++mt) aO[mt] = ldHfrag(HsXF, mt, kO);
#pragma unroll
                for (int nt = 0; nt < 2; ++nt)
                    bO[nt] = *(const bf16x8*)(W + voff[nt] + (kO << 5));
            }
        }
        // tail kt=8 (dir) — aE/bE hold it after the kt=6 iteration's refill
        __builtin_amdgcn_s_setprio(1);
#pragma unroll
        for (int nt = 0; nt < 2; ++nt)
#pragma unroll
            for (int mt = 0; mt < 4; ++mt)
                acc[mt][nt] = MFMA16(bE[nt], aE[mt], acc[mt][nt]);
        __builtin_amdgcn_s_setprio(0);

#pragma unroll
        for (int nt = 0; nt < 2; ++nt) {
#pragma unroll
            for (int mt = 0; mt < 4; ++mt) {
                f32x4 v = acc[mt][nt];
#pragma unroll
                for (int e = 0; e < 4; ++e) v[e] = fmaxf(v[e], 0.f);
                unsigned int lo, hi;
                asm("v_cvt_pk_bf16_f32 %0, %1, %2" : "=v"(lo) : "v"(v[0]), "v"(v[1]));
                asm("v_cvt_pk_bf16_f32 %0, %1, %2" : "=v"(hi) : "v"(v[2]), "v"(v[3]));
                int colb = (cb + (nt << 4) + (lk << 2)) << 1;
                int off = rowOff[mt] + (colb ^ swz[mt]);
                uint32x2 w2 = {lo, hi};
                *(uint32x2*)(HsH + off) = w2;
            }
        }
        soft_barrier();
    }

    // rgb = sigmoid(d @ wr + br); fused float4 store {r,g,b,sigma}
    {
        int rr = t >> 2, q = t & 3;
        float c0 = 0.f, c1 = 0.f, c2 = 0.f;
#pragma unroll
        for (int j = 0; j < 4; ++j) {
            int kb = (q << 5) + (j << 3);
            bf16x8 d8 = *(const bf16x8*)(HsH + ((rr * 512 + (kb << 1)) ^ ((rr & 7) << 4)));
#pragma unroll
            for (int e = 0; e < 8; ++e) {
                float dv = (float)d8[e];
                const float* w = P.wrv + (kb + e) * 3;
                c0 += dv * w[0]; c1 += dv * w[1]; c2 += dv * w[2];
            }
        }
        c0 += __shfl_xor(c0, 1); c0 += __shfl_xor(c0, 2);
        c1 += __shfl_xor(c1, 1); c1 += __shfl_xor(c1, 2);
        c2 += __shfl_xor(c2, 1); c2 += __shfl_xor(c2, 2);
        if (q == 0) {
            float4 o;
            o.x = 1.f / (1.f + __expf(-(c0 + P.brv[0])));
            o.y = 1.f / (1.f + __expf(-(c1 + P.brv[1])));
            o.z = 1.f / (1.f + __expf(-(c2 + P.brv[2])));
            o.w = sig;
            ((float4*)P.out)[blockRow + rr] = o;
        }
    }
}

extern "C" void kernel_launch(void* const* d_in, const int* in_sizes, int n_in,
                              void* d_out, int out_size, void* d_ws, size_t ws_size,
                              hipStream_t stream) {
    const float* x = (const float*)d_in[0];
    const float* w[8];
    const float* b[8];
    for (int i = 0; i < 8; ++i) {
        w[i] = (const float*)d_in[1 + 2 * i];
        b[i] = (const float*)d_in[2 + 2 * i];
    }
    const float* wf  = (const float*)d_in[17];
    const float* bfv = (const float*)d_in[18];
    const float* wd  = (const float*)d_in[19];
    const float* bdv = (const float*)d_in[20];
    const float* wsv = (const float*)d_in[21];
    const float* bsv = (const float*)d_in[22];
    const float* wrv = (const float*)d_in[23];
    const float* brv = (const float*)d_in[24];

    unsigned short* Wt = (unsigned short*)d_ws;
    const float** tbl = (const float**)((char*)d_ws + (size_t)W_TOTAL * 2);

    prep_kernel<<<(W_TOTAL + 255) / 256, 256, 0, stream>>>(
        w[0], w[1], w[2], w[3], w[4], w[5], w[6], w[7], wf, wd,
        b[0], b[1], b[2], b[3], b[4], b[5], b[6], b[7], bfv,
        Wt, tbl);

    Params P;
    P.x = x; P.Wt = Wt; P.bias9 = tbl;
    P.bdv = bdv; P.wsv = wsv; P.bsv = bsv; P.wrv = wrv; P.brv = brv;
    P.out = (float*)d_out;

    nerf_kernel<<<262144 / 64, 256, 0, stream>>>(P);
}